// Round 17
// baseline (109.093 us; speedup 1.0000x reference)
//
#include <hip/hip_runtime.h>

#define B_ 4
#define C_ 256
#define T_ 2304
#define HD 32
#define GSZ (32 * T_)                 // elems per groupnorm group = 73728
#define SCL2E (0.17677669529663687f * 1.44269504088896f)  // (1/sqrt(32)) * log2(e)

typedef short bf16x8 __attribute__((ext_vector_type(8)));
typedef float f32x4 __attribute__((ext_vector_type(4)));
typedef unsigned int u32x2 __attribute__((ext_vector_type(2)));

__device__ inline unsigned short f2bf(float f) {
  unsigned int u = __float_as_uint(f);
  return (unsigned short)((u + 0x7FFFu + ((u >> 16) & 1u)) >> 16);
}

__device__ inline float fexp2(float x) {
  float r;
  asm("v_exp_f32 %0, %1" : "=v"(r) : "v"(x));
  return r;
}

__device__ inline unsigned cvtpk(float lo, float hi) {
  unsigned r;
  asm("v_cvt_pk_bf16_f32 %0, %1, %2" : "=v"(r) : "v"(lo), "v"(hi));
  return r;
}

// ---------------- weights -> bf16  +  groupnorm partial stats (merged) ----------------
__global__ void prep(const float* wq, const float* wp, const float* x,
                     unsigned short* oq, unsigned short* op, float* ws1) {
  if (blockIdx.x < 1024) {
    int i = blockIdx.x * 256 + threadIdx.x;
    const int n1 = 3 * C_ * C_;
    if (i < n1) oq[i] = f2bf(wq[i]);
    else        op[i - n1] = f2bf(wp[i - n1]);
    return;
  }
  int bid = blockIdx.x - 1024;
  int bg = bid >> 3, sl = bid & 7;
  const float4* p = (const float4*)(x + (size_t)bg * GSZ + sl * (GSZ / 8));
  float s = 0.f, q = 0.f;
  for (int it = 0; it < 9; ++it) {
    float4 v = p[it * 256 + threadIdx.x];
    s += v.x + v.y + v.z + v.w;
    q += v.x * v.x + v.y * v.y + v.z * v.z + v.w * v.w;
  }
  for (int off = 32; off; off >>= 1) {
    s += __shfl_down(s, off);
    q += __shfl_down(q, off);
  }
  __shared__ float red[8];
  int w = threadIdx.x >> 6;
  if ((threadIdx.x & 63) == 0) { red[w * 2] = s; red[w * 2 + 1] = q; }
  __syncthreads();
  if (threadIdx.x == 0) {
    float S = red[0] + red[2] + red[4] + red[6];
    float Q = red[1] + red[3] + red[5] + red[7];
    ws1[bid * 2] = S;
    ws1[bid * 2 + 1] = Q;
  }
}

// ---------------- groupnorm: finalize stats (inline) + normalize + transpose to nT[B][T][C] --
__global__ void gn_norm(const float* x, const float* ws1, const float* gamma,
                        const float* beta, unsigned short* nT) {
  int b = blockIdx.y, t0 = blockIdx.x * 32;
  __shared__ unsigned short tile[32 * 264];
  __shared__ float stl[16];
  int tid = threadIdx.x;
  if (tid < 8) {
    float S = 0.f, Q = 0.f;
    for (int sl = 0; sl < 8; ++sl) {
      S += ws1[((b * 8 + tid) * 8 + sl) * 2];
      Q += ws1[((b * 8 + tid) * 8 + sl) * 2 + 1];
    }
    float mean = S / (float)GSZ;
    float var = Q / (float)GSZ - mean * mean;
    stl[tid * 2] = mean;
    stl[tid * 2 + 1] = rsqrtf(var + 1e-5f);
  }
  __syncthreads();
#pragma unroll
  for (int it = 0; it < 8; ++it) {
    int qd = it * 256 + tid;
    int c = qd >> 3, tq = qd & 7;
    float4 v = *(const float4*)&x[((size_t)b * C_ + c) * T_ + t0 + tq * 4];
    int g = c >> 5;
    float mean = stl[g * 2], rstd = stl[g * 2 + 1];
    float sc = rstd * gamma[c];
    float sh = beta[c] - mean * sc;
    tile[(tq * 4 + 0) * 264 + c] = f2bf(v.x * sc + sh);
    tile[(tq * 4 + 1) * 264 + c] = f2bf(v.y * sc + sh);
    tile[(tq * 4 + 2) * 264 + c] = f2bf(v.z * sc + sh);
    tile[(tq * 4 + 3) * 264 + c] = f2bf(v.w * sc + sh);
  }
  __syncthreads();
#pragma unroll
  for (int it = 0; it < 4; ++it) {
    int qd = it * 256 + tid;
    int tt = qd >> 5, c8 = (qd & 31) * 8;
    *(uint4*)&nT[((size_t)b * T_ + t0 + tt) * C_ + c8] = *(const uint4*)&tile[tt * 264 + c8];
  }
}

// ---------------- QKV GEMM: [768,256] x nT -> qT/kT [b,h,t,d], v [b,h,d,t-permuted] --------
// V t-positions permuted within each 32-block: pos = 8g+4e+i for s=16e+4g+i, so attn's
// V fragment is a single b128 in kappa-slot order.
__global__ __launch_bounds__(256) void qkv_gemm(const unsigned short* W, const unsigned short* nT,
                                                const float* bias, unsigned short* qT,
                                                unsigned short* kT, unsigned short* vW) {
  __shared__ unsigned short tt[64][72];
  int b = blockIdx.z;
  int lane = threadIdx.x & 63, w = threadIdx.x >> 6;
  int r16 = lane & 15, g4 = lane >> 4;
  int y = blockIdx.y;
  int type = y >> 2;                    // 0=q 1=k 2=v
  int m0 = y * 64 + (w >> 1) * 32;
  int n0 = blockIdx.x * 64 + (w & 1) * 32;
  const bf16x8* Wv = (const bf16x8*)W;
  const bf16x8* Nv = (const bf16x8*)(nT + (size_t)b * T_ * C_);
  f32x4 acc[2][2] = {};
  for (int k0 = 0; k0 < C_; k0 += 32) {
    bf16x8 af[2], bfr[2];
    for (int mi = 0; mi < 2; ++mi)
      af[mi] = Wv[((m0 + mi * 16 + r16) * C_ + k0 + g4 * 8) >> 3];
    for (int ni = 0; ni < 2; ++ni)
      bfr[ni] = Nv[((n0 + ni * 16 + r16) * C_ + k0 + g4 * 8) >> 3];
    for (int mi = 0; mi < 2; ++mi)
      for (int ni = 0; ni < 2; ++ni)
        acc[mi][ni] = __builtin_amdgcn_mfma_f32_16x16x32_bf16(af[mi], bfr[ni], acc[mi][ni], 0, 0, 0);
  }
#pragma unroll
  for (int mi = 0; mi < 2; ++mi) {
#pragma unroll
    for (int ni = 0; ni < 2; ++ni) {
      int t_loc = (w & 1) * 32 + ni * 16 + r16;
      int o_loc = (w >> 1) * 32 + mi * 16 + g4 * 4;
      int o = y * 64 + o_loc;
      float v0 = acc[mi][ni][0] + bias[o + 0];
      float v1 = acc[mi][ni][1] + bias[o + 1];
      float v2 = acc[mi][ni][2] + bias[o + 2];
      float v3 = acc[mi][ni][3] + bias[o + 3];
      if (type == 0) { v0 *= SCL2E; v1 *= SCL2E; v2 *= SCL2E; v3 *= SCL2E; }
      if (type < 2) {
        u32x2 pw = {cvtpk(v0, v1), cvtpk(v2, v3)};
        *(u32x2*)&tt[t_loc][o_loc] = pw;          // [t][o]
      } else {
        // V: permute t within its 32-block: s5=16e+4g+i -> pos=8g+4e+i
        int s5 = t_loc & 31;
        int e = s5 >> 4, r4 = s5 & 15;
        int tp = (t_loc & 32) | (((r4 >> 2) << 3) + (e << 2) + (r4 & 3));
        tt[o_loc + 0][tp] = f2bf(v0);             // [o][t-permuted]
        tt[o_loc + 1][tp] = f2bf(v1);
        tt[o_loc + 2][tp] = f2bf(v2);
        tt[o_loc + 3][tp] = f2bf(v3);
      }
    }
  }
  __syncthreads();
  int tid = threadIdx.x;
  if (type < 2) {
    unsigned short* dst = (type == 0) ? qT : kT;
    int obase = y * 64 - type * 256;
    int t_loc = tid >> 2;
    int tg = blockIdx.x * 64 + t_loc;
#pragma unroll
    for (int half = 0; half < 2; ++half) {
      int o_loc = half * 32 + (tid & 3) * 8;
      int o2 = obase + o_loc;
      int hh = o2 >> 5, d = o2 & 31;
      *(uint4*)&dst[(((size_t)b * 8 + hh) * T_ + tg) * HD + d] = *(const uint4*)&tt[t_loc][o_loc];
    }
  } else {
    int obase = y * 64 - 512;
    int o_loc = tid >> 2;
    int o2 = obase + o_loc;
    int hh = o2 >> 5, d = o2 & 31;
    unsigned short* vdst = vW + ((size_t)(b * 8 + hh) * HD + d) * T_ + blockIdx.x * 64;
#pragma unroll
    for (int half = 0; half < 2; ++half) {
      int t_loc = half * 32 + (tid & 3) * 8;
      *(uint4*)&vdst[t_loc] = *(const uint4*)&tt[o_loc][t_loc];
    }
  }
}

// ---------------- flash attention: 32-s tiles, 2 s-parts x 2 q-waves, in-block combine ------
// Halved tiles: block LDS 20.5KB -> up to 7 blocks/CU resident. V frag = single b128
// (pre-permuted layout). Same kappa-paired register-PV math as R16.
__global__ __launch_bounds__(256) void attn(const unsigned short* qT, const unsigned short* kT,
                                            const unsigned short* vW, unsigned short* aT) {
  int b = blockIdx.z, h = blockIdx.y, qt = blockIdx.x;
  int tid = threadIdx.x, lane = tid & 63, w = tid >> 6;  // w in {0..3}
  int part = w >> 1, wsub = w & 1;
  int r16 = lane & 15, g4 = lane >> 4;
  __shared__ short Ks[2][2][32 * 40];   // [part][buf][s=32][d=32 pad40]
  __shared__ short Vs[2][2][32 * 40];   // [part][buf][d=32][s=32-permuted pad40]
  const unsigned short* qB = qT + ((size_t)b * 8 + h) * T_ * HD;
  const unsigned short* kB = kT + ((size_t)b * 8 + h) * T_ * HD;
  const unsigned short* vB = vW + ((size_t)b * 8 + h) * HD * T_;
  int qbase = qt * 64 + wsub * 32;      // wave owns q-rows [qbase, qbase+32)
  bf16x8 qfA = *(const bf16x8*)(qB + (qbase + r16) * HD + g4 * 8);
  bf16x8 qfB = *(const bf16x8*)(qB + (qbase + 16 + r16) * HD + g4 * 8);
  float lA = 0.f, lB = 0.f;
  f32x4 accA0 = {}, accA1 = {}, accB0 = {}, accB1 = {};
  int t0 = part * 36;                   // 72 tiles of 32 s, halves per part

  // staging: each 2-wave part (128 threads) stages its 2KB K-tile + 2KB V-tile (1 b128 each)
  int tp = tid & 127;
  int srow = tp >> 2, scol = (tid & 3) * 8;   // 32 rows x 4 chunks
  const unsigned short* kSrc = kB + (size_t)srow * HD + scol;
  const unsigned short* vSrc = vB + (size_t)srow * T_ + scol;
  int4 rgK, rgV;

  union PU { unsigned u[4]; bf16x8 v; };

#define LOADT(t_) {                                                               \
    rgK = *(const int4*)(kSrc + (size_t)(t_) * 32 * HD);                          \
    rgV = *(const int4*)(vSrc + (t_) * 32);                                       \
  }

#define STORET(bi) {                                                              \
    *(int4*)&Ks[part][bi][srow * 40 + scol] = rgK;                                \
    *(int4*)&Vs[part][bi][srow * 40 + scol] = rgV;                                \
  }

// QK -> exp -> pack (lane-local) -> PV through registers. kappa(g4,j) = 4g4+(j&3)+16(j>>2).
#define SUBTILE(qf, lsum, acc0, acc1) {                                           \
    f32x4 z = {};                                                                 \
    f32x4 s0 = __builtin_amdgcn_mfma_f32_16x16x32_bf16(kf0, qf, z, 0, 0, 0);      \
    f32x4 s1 = __builtin_amdgcn_mfma_f32_16x16x32_bf16(kf1, qf, z, 0, 0, 0);      \
    float p0 = fexp2(s0[0]), p1 = fexp2(s0[1]), p2 = fexp2(s0[2]), p3 = fexp2(s0[3]); \
    float p4 = fexp2(s1[0]), p5 = fexp2(s1[1]), p6 = fexp2(s1[2]), p7 = fexp2(s1[3]); \
    float ps = ((p0 + p1) + (p2 + p3)) + ((p4 + p5) + (p6 + p7));                 \
    PU w0;                                                                        \
    w0.u[0] = cvtpk(p0, p1); w0.u[1] = cvtpk(p2, p3);                             \
    w0.u[2] = cvtpk(p4, p5); w0.u[3] = cvtpk(p6, p7);                             \
    ps += __shfl_xor(ps, 16);                                                     \
    ps += __shfl_xor(ps, 32);                                                     \
    lsum += ps;                                                                   \
    acc0 = __builtin_amdgcn_mfma_f32_16x16x32_bf16(vf0, w0.v, acc0, 0, 0, 0);     \
    acc1 = __builtin_amdgcn_mfma_f32_16x16x32_bf16(vf1, w0.v, acc1, 0, 0, 0);     \
  }

  // prologue: tile t0 -> buf0, tile t0+1 -> regs
  LOADT(t0)
  STORET(0)
  LOADT(t0 + 1)
  __syncthreads();

  for (int t = 0; t < 36; ++t) {
    int bi = t & 1;
    if (t < 35) STORET(bi ^ 1)          // tile t+1: regs -> other buffer
    if (t < 34) LOADT(t0 + t + 2)       // tile t+2: global -> regs

    const short* Kc = &Ks[part][bi][0];
    const short* Vc = &Vs[part][bi][0];
    bf16x8 kf0 = *(const bf16x8*)&Kc[(r16) * 40 + g4 * 8];
    bf16x8 kf1 = *(const bf16x8*)&Kc[(16 + r16) * 40 + g4 * 8];
    bf16x8 vf0 = *(const bf16x8*)&Vc[(r16) * 40 + g4 * 8];        // d rows [0,16)
    bf16x8 vf1 = *(const bf16x8*)&Vc[(16 + r16) * 40 + g4 * 8];   // d rows [16,32)

    SUBTILE(qfA, lA, accA0, accA1)
    SUBTILE(qfB, lB, accB0, accB1)

    __syncthreads();                    // tile t consumed; tile t+1 stores visible
  }

  // ---- in-block combine: part1 -> LDS (dead Ks space, 10KB), part0 adds + writes ----
  float* ex = (float*)&Ks[0][0][0];     // 2 waves x 64 lanes x 16 f32 = 8 KB
  float* lex = ex + 2048;               // 2 waves x 64 lanes x 2 f32 (fits in Ks' 10.2KB)
  if (part == 1) {
    f32x4* dst = (f32x4*)&ex[(wsub * 64 + lane) * 16];
    dst[0] = accA0; dst[1] = accA1; dst[2] = accB0; dst[3] = accB1;
    lex[(wsub * 64 + lane) * 2] = lA;
    lex[(wsub * 64 + lane) * 2 + 1] = lB;
  }
  __syncthreads();
  if (part == 0) {
    const f32x4* src = (const f32x4*)&ex[(wsub * 64 + lane) * 16];
    accA0 += src[0]; accA1 += src[1]; accB0 += src[2]; accB1 += src[3];
    lA += lex[(wsub * 64 + lane) * 2];
    lB += lex[(wsub * 64 + lane) * 2 + 1];
    float invA = 1.f / lA;
    float invB = 1.f / lB;
    unsigned short* oA = aT + ((size_t)b * T_ + qbase + r16) * C_ + h * HD + 4 * g4;
    unsigned short* oB = aT + ((size_t)b * T_ + qbase + 16 + r16) * C_ + h * HD + 4 * g4;
    u32x2 wA0 = {cvtpk(accA0[0] * invA, accA0[1] * invA), cvtpk(accA0[2] * invA, accA0[3] * invA)};
    u32x2 wA1 = {cvtpk(accA1[0] * invA, accA1[1] * invA), cvtpk(accA1[2] * invA, accA1[3] * invA)};
    u32x2 wB0 = {cvtpk(accB0[0] * invB, accB0[1] * invB), cvtpk(accB0[2] * invB, accB0[3] * invB)};
    u32x2 wB1 = {cvtpk(accB1[0] * invB, accB1[1] * invB), cvtpk(accB1[2] * invB, accB1[3] * invB)};
    *(u32x2*)oA = wA0;
    *(u32x2*)(oA + 16) = wA1;
    *(u32x2*)oB = wB0;
    *(u32x2*)(oB + 16) = wB1;
  }
#undef LOADT
#undef STORET
#undef SUBTILE
}

// ---------------- proj GEMM + bias + residual ----------------
__global__ __launch_bounds__(256) void proj_gemm(const unsigned short* W, const unsigned short* aT,
                                                 const float* bias, const float* x, float* out) {
  int b = blockIdx.z;
  int lane = threadIdx.x & 63, w = threadIdx.x >> 6;
  int r16 = lane & 15, g4 = lane >> 4;
  int m0 = blockIdx.y * 64 + (w >> 1) * 32;
  int n0 = blockIdx.x * 64 + (w & 1) * 32;
  const bf16x8* Wv = (const bf16x8*)W;
  const bf16x8* Av = (const bf16x8*)(aT + (size_t)b * T_ * C_);
  f32x4 acc[2][2] = {};
  for (int k0 = 0; k0 < C_; k0 += 32) {
    bf16x8 af[2], bfr[2];
    for (int mi = 0; mi < 2; ++mi)
      af[mi] = Wv[((m0 + mi * 16 + r16) * C_ + k0 + g4 * 8) >> 3];
    for (int ni = 0; ni < 2; ++ni)
      bfr[ni] = Av[((n0 + ni * 16 + r16) * C_ + k0 + g4 * 8) >> 3];
    for (int mi = 0; mi < 2; ++mi)
      for (int ni = 0; ni < 2; ++ni)
        acc[mi][ni] = __builtin_amdgcn_mfma_f32_16x16x32_bf16(af[mi], bfr[ni], acc[mi][ni], 0, 0, 0);
  }
  for (int mi = 0; mi < 2; ++mi)
    for (int ni = 0; ni < 2; ++ni) {
      int t = n0 + ni * 16 + r16;
      for (int r = 0; r < 4; ++r) {
        int o = m0 + mi * 16 + g4 * 4 + r;
        size_t idx = ((size_t)b * C_ + o) * T_ + t;
        out[idx] = x[idx] + acc[mi][ni][r] + bias[o];
      }
    }
}

extern "C" void kernel_launch(void* const* d_in, const int* in_sizes, int n_in,
                              void* d_out, int out_size, void* d_ws, size_t ws_size,
                              hipStream_t stream) {
  const float* x  = (const float*)d_in[0];
  const float* gw = (const float*)d_in[1];
  const float* gb = (const float*)d_in[2];
  const float* wq = (const float*)d_in[3];
  const float* bq = (const float*)d_in[4];
  const float* wp = (const float*)d_in[5];
  const float* bp = (const float*)d_in[6];

  char* ws = (char*)d_ws;
  float* ws1 = (float*)ws;                       // 256*2 f32
  unsigned short* wqb = (unsigned short*)(ws + 4096);
  unsigned short* wpb = wqb + 3 * C_ * C_;
  unsigned short* nT  = wpb + C_ * C_;
  const size_t NE = (size_t)B_ * T_ * C_;        // 2359296
  unsigned short* qT = nT + NE;
  unsigned short* kT = qT + NE;
  unsigned short* vW = kT + NE;
  unsigned short* aT = vW + NE;

  prep<<<1280, 256, 0, stream>>>(wq, wp, x, wqb, wpb, ws1);
  gn_norm<<<dim3(72, 4), 256, 0, stream>>>(x, ws1, gw, gb, nT);
  qkv_gemm<<<dim3(36, 12, 4), 256, 0, stream>>>(wqb, nT, bq, qT, kT, vW);
  attn<<<dim3(36, 8, 4), 256, 0, stream>>>(qT, kT, vW, aT);
  proj_gemm<<<dim3(36, 4, 4), 256, 0, stream>>>(wpb, aT, bp, x, (float*)d_out);
}

// Round 18
// 106.441 us; speedup vs baseline: 1.0249x; 1.0249x over previous
//
#include <hip/hip_runtime.h>

#define B_ 4
#define C_ 256
#define T_ 2304
#define HD 32
#define GSZ (32 * T_)                 // elems per groupnorm group = 73728
#define SCL2E (0.17677669529663687f * 1.44269504088896f)  // (1/sqrt(32)) * log2(e)

typedef short bf16x8 __attribute__((ext_vector_type(8)));
typedef float f32x4 __attribute__((ext_vector_type(4)));
typedef unsigned int u32x2 __attribute__((ext_vector_type(2)));

__device__ inline unsigned short f2bf(float f) {
  unsigned int u = __float_as_uint(f);
  return (unsigned short)((u + 0x7FFFu + ((u >> 16) & 1u)) >> 16);
}

__device__ inline float fexp2(float x) {
  float r;
  asm("v_exp_f32 %0, %1" : "=v"(r) : "v"(x));
  return r;
}

__device__ inline unsigned cvtpk(float lo, float hi) {
  unsigned r;
  asm("v_cvt_pk_bf16_f32 %0, %1, %2" : "=v"(r) : "v"(lo), "v"(hi));
  return r;
}

// ---------------- weights -> bf16  +  groupnorm partial stats (merged) ----------------
__global__ void prep(const float* wq, const float* wp, const float* x,
                     unsigned short* oq, unsigned short* op, float* ws1) {
  if (blockIdx.x < 1024) {
    int i = blockIdx.x * 256 + threadIdx.x;
    const int n1 = 3 * C_ * C_;
    if (i < n1) oq[i] = f2bf(wq[i]);
    else        op[i - n1] = f2bf(wp[i - n1]);
    return;
  }
  int bid = blockIdx.x - 1024;
  int bg = bid >> 3, sl = bid & 7;
  const float4* p = (const float4*)(x + (size_t)bg * GSZ + sl * (GSZ / 8));
  float s = 0.f, q = 0.f;
  for (int it = 0; it < 9; ++it) {
    float4 v = p[it * 256 + threadIdx.x];
    s += v.x + v.y + v.z + v.w;
    q += v.x * v.x + v.y * v.y + v.z * v.z + v.w * v.w;
  }
  for (int off = 32; off; off >>= 1) {
    s += __shfl_down(s, off);
    q += __shfl_down(q, off);
  }
  __shared__ float red[8];
  int w = threadIdx.x >> 6;
  if ((threadIdx.x & 63) == 0) { red[w * 2] = s; red[w * 2 + 1] = q; }
  __syncthreads();
  if (threadIdx.x == 0) {
    float S = red[0] + red[2] + red[4] + red[6];
    float Q = red[1] + red[3] + red[5] + red[7];
    ws1[bid * 2] = S;
    ws1[bid * 2 + 1] = Q;
  }
}

// ---------------- groupnorm: finalize stats (inline) + normalize + transpose to nT[B][T][C] --
__global__ void gn_norm(const float* x, const float* ws1, const float* gamma,
                        const float* beta, unsigned short* nT) {
  int b = blockIdx.y, t0 = blockIdx.x * 32;
  __shared__ unsigned short tile[32 * 264];
  __shared__ float stl[16];
  int tid = threadIdx.x;
  if (tid < 8) {
    float S = 0.f, Q = 0.f;
    for (int sl = 0; sl < 8; ++sl) {
      S += ws1[((b * 8 + tid) * 8 + sl) * 2];
      Q += ws1[((b * 8 + tid) * 8 + sl) * 2 + 1];
    }
    float mean = S / (float)GSZ;
    float var = Q / (float)GSZ - mean * mean;
    stl[tid * 2] = mean;
    stl[tid * 2 + 1] = rsqrtf(var + 1e-5f);
  }
  __syncthreads();
#pragma unroll
  for (int it = 0; it < 8; ++it) {
    int qd = it * 256 + tid;
    int c = qd >> 3, tq = qd & 7;
    float4 v = *(const float4*)&x[((size_t)b * C_ + c) * T_ + t0 + tq * 4];
    int g = c >> 5;
    float mean = stl[g * 2], rstd = stl[g * 2 + 1];
    float sc = rstd * gamma[c];
    float sh = beta[c] - mean * sc;
    tile[(tq * 4 + 0) * 264 + c] = f2bf(v.x * sc + sh);
    tile[(tq * 4 + 1) * 264 + c] = f2bf(v.y * sc + sh);
    tile[(tq * 4 + 2) * 264 + c] = f2bf(v.z * sc + sh);
    tile[(tq * 4 + 3) * 264 + c] = f2bf(v.w * sc + sh);
  }
  __syncthreads();
#pragma unroll
  for (int it = 0; it < 4; ++it) {
    int qd = it * 256 + tid;
    int tt = qd >> 5, c8 = (qd & 31) * 8;
    *(uint4*)&nT[((size_t)b * T_ + t0 + tt) * C_ + c8] = *(const uint4*)&tile[tt * 264 + c8];
  }
}

// ---------------- QKV GEMM: [768,256] x nT -> qT/kT [b,h,t,d], v [b,h,d,t-permuted] --------
// V t-positions permuted within each 32-block: pos = 8g+4e+i for s=16e+4g+i, so attn's
// V fragment is a single b128 in kappa-slot order.
__global__ __launch_bounds__(256) void qkv_gemm(const unsigned short* W, const unsigned short* nT,
                                                const float* bias, unsigned short* qT,
                                                unsigned short* kT, unsigned short* vW) {
  __shared__ unsigned short tt[64][72];
  int b = blockIdx.z;
  int lane = threadIdx.x & 63, w = threadIdx.x >> 6;
  int r16 = lane & 15, g4 = lane >> 4;
  int y = blockIdx.y;
  int type = y >> 2;                    // 0=q 1=k 2=v
  int m0 = y * 64 + (w >> 1) * 32;
  int n0 = blockIdx.x * 64 + (w & 1) * 32;
  const bf16x8* Wv = (const bf16x8*)W;
  const bf16x8* Nv = (const bf16x8*)(nT + (size_t)b * T_ * C_);
  f32x4 acc[2][2] = {};
  for (int k0 = 0; k0 < C_; k0 += 32) {
    bf16x8 af[2], bfr[2];
    for (int mi = 0; mi < 2; ++mi)
      af[mi] = Wv[((m0 + mi * 16 + r16) * C_ + k0 + g4 * 8) >> 3];
    for (int ni = 0; ni < 2; ++ni)
      bfr[ni] = Nv[((n0 + ni * 16 + r16) * C_ + k0 + g4 * 8) >> 3];
    for (int mi = 0; mi < 2; ++mi)
      for (int ni = 0; ni < 2; ++ni)
        acc[mi][ni] = __builtin_amdgcn_mfma_f32_16x16x32_bf16(af[mi], bfr[ni], acc[mi][ni], 0, 0, 0);
  }
#pragma unroll
  for (int mi = 0; mi < 2; ++mi) {
#pragma unroll
    for (int ni = 0; ni < 2; ++ni) {
      int t_loc = (w & 1) * 32 + ni * 16 + r16;
      int o_loc = (w >> 1) * 32 + mi * 16 + g4 * 4;
      int o = y * 64 + o_loc;
      float v0 = acc[mi][ni][0] + bias[o + 0];
      float v1 = acc[mi][ni][1] + bias[o + 1];
      float v2 = acc[mi][ni][2] + bias[o + 2];
      float v3 = acc[mi][ni][3] + bias[o + 3];
      if (type == 0) { v0 *= SCL2E; v1 *= SCL2E; v2 *= SCL2E; v3 *= SCL2E; }
      if (type < 2) {
        u32x2 pw = {cvtpk(v0, v1), cvtpk(v2, v3)};
        *(u32x2*)&tt[t_loc][o_loc] = pw;          // [t][o]
      } else {
        // V: permute t within its 32-block: s5=16e+4g+i -> pos=8g+4e+i
        int s5 = t_loc & 31;
        int e = s5 >> 4, r4 = s5 & 15;
        int tp = (t_loc & 32) | (((r4 >> 2) << 3) + (e << 2) + (r4 & 3));
        tt[o_loc + 0][tp] = f2bf(v0);             // [o][t-permuted]
        tt[o_loc + 1][tp] = f2bf(v1);
        tt[o_loc + 2][tp] = f2bf(v2);
        tt[o_loc + 3][tp] = f2bf(v3);
      }
    }
  }
  __syncthreads();
  int tid = threadIdx.x;
  if (type < 2) {
    unsigned short* dst = (type == 0) ? qT : kT;
    int obase = y * 64 - type * 256;
    int t_loc = tid >> 2;
    int tg = blockIdx.x * 64 + t_loc;
#pragma unroll
    for (int half = 0; half < 2; ++half) {
      int o_loc = half * 32 + (tid & 3) * 8;
      int o2 = obase + o_loc;
      int hh = o2 >> 5, d = o2 & 31;
      *(uint4*)&dst[(((size_t)b * 8 + hh) * T_ + tg) * HD + d] = *(const uint4*)&tt[t_loc][o_loc];
    }
  } else {
    int obase = y * 64 - 512;
    int o_loc = tid >> 2;
    int o2 = obase + o_loc;
    int hh = o2 >> 5, d = o2 & 31;
    unsigned short* vdst = vW + ((size_t)(b * 8 + hh) * HD + d) * T_ + blockIdx.x * 64;
#pragma unroll
    for (int half = 0; half < 2; ++half) {
      int t_loc = half * 32 + (tid & 3) * 8;
      *(uint4*)&vdst[t_loc] = *(const uint4*)&tt[o_loc][t_loc];
    }
  }
}

// ---------------- flash attention: R16 structure + b128 V-frags + unrolled x2 loop ----------
// 4 waves = 2 s-parts x 2 q-waves; 64-s tiles double-buffered; in-block combine.
__global__ __launch_bounds__(256) void attn(const unsigned short* qT, const unsigned short* kT,
                                            const unsigned short* vW, unsigned short* aT) {
  int b = blockIdx.z, h = blockIdx.y, qt = blockIdx.x;
  int tid = threadIdx.x, lane = tid & 63, w = tid >> 6;  // w in {0..3}
  int part = w >> 1, wsub = w & 1;
  int r16 = lane & 15, g4 = lane >> 4;
  __shared__ short Ks[2][2][64 * 40];   // [part][buf][s][d] padded to 40
  __shared__ short Vs[2][2][32 * 72];   // [part][buf][d][s-permuted] padded to 72
  const unsigned short* qB = qT + ((size_t)b * 8 + h) * T_ * HD;
  const unsigned short* kB = kT + ((size_t)b * 8 + h) * T_ * HD;
  const unsigned short* vB = vW + ((size_t)b * 8 + h) * HD * T_;
  int qbase = qt * 64 + wsub * 32;      // wave owns q-rows [qbase, qbase+32)
  bf16x8 qfA = *(const bf16x8*)(qB + (qbase + r16) * HD + g4 * 8);
  bf16x8 qfB = *(const bf16x8*)(qB + (qbase + 16 + r16) * HD + g4 * 8);
  float lA = 0.f, lB = 0.f;
  f32x4 accA0 = {}, accA1 = {}, accB0 = {}, accB1 = {};
  int t0p = part * 18;

  // staging: each 2-wave part (128 threads) stages its own tileset, 4x b128 per thread
  int tp = tid & 127;
  int krow = tp >> 2, kcol = (tid & 3) * 8;   // K rows krow, krow+32
  int vrow = tp >> 3, vcol = (tid & 7) * 8;   // V rows vrow, vrow+16
  const unsigned short* kSrc = kB + (size_t)krow * HD + kcol;
  const unsigned short* vSrc = vB + (size_t)vrow * T_ + vcol;
  int4 rgK0, rgK1, rgV0, rgV1;

  union PU { unsigned u[4]; bf16x8 v; };

  // hoisted per-buffer bases (static after unroll)
  const short* Kc0 = &Ks[part][0][0];
  const short* Kc1 = &Ks[part][1][0];
  const short* Vc0 = &Vs[part][0][0];
  const short* Vc1 = &Vs[part][1][0];
  short* kD0 = &Ks[part][0][krow * 40 + kcol];
  short* kD1 = &Ks[part][1][krow * 40 + kcol];
  short* vD0 = &Vs[part][0][vrow * 72 + vcol];
  short* vD1 = &Vs[part][1][vrow * 72 + vcol];

#define LOADT(t_) {                                                               \
    const unsigned short* k_ = kSrc + (t_) * 64 * HD;                             \
    rgK0 = *(const int4*)k_;                                                      \
    rgK1 = *(const int4*)(k_ + 32 * HD);                                          \
    const unsigned short* v_ = vSrc + (t_) * 64;                                  \
    rgV0 = *(const int4*)v_;                                                      \
    rgV1 = *(const int4*)(v_ + (size_t)16 * T_);                                  \
  }

#define STORET(kD, vD) {                                                          \
    *(int4*)kD = rgK0;                                                            \
    *(int4*)(kD + 32 * 40) = rgK1;                                                \
    *(int4*)vD = rgV0;                                                            \
    *(int4*)(vD + 16 * 72) = rgV1;                                                \
  }

#define SUBTILE(qf, lsum, acc0, acc1) {                                           \
    f32x4 z = {};                                                                 \
    f32x4 s0 = __builtin_amdgcn_mfma_f32_16x16x32_bf16(kf0, qf, z, 0, 0, 0);      \
    f32x4 s1 = __builtin_amdgcn_mfma_f32_16x16x32_bf16(kf1, qf, z, 0, 0, 0);      \
    f32x4 s2 = __builtin_amdgcn_mfma_f32_16x16x32_bf16(kf2, qf, z, 0, 0, 0);      \
    f32x4 s3 = __builtin_amdgcn_mfma_f32_16x16x32_bf16(kf3, qf, z, 0, 0, 0);      \
    float p0 = fexp2(s0[0]), p1 = fexp2(s0[1]), p2 = fexp2(s0[2]), p3 = fexp2(s0[3]); \
    float p4 = fexp2(s1[0]), p5 = fexp2(s1[1]), p6 = fexp2(s1[2]), p7 = fexp2(s1[3]); \
    float p8 = fexp2(s2[0]), p9 = fexp2(s2[1]), pa = fexp2(s2[2]), pb = fexp2(s2[3]); \
    float pc = fexp2(s3[0]), pd = fexp2(s3[1]), pe = fexp2(s3[2]), pf = fexp2(s3[3]); \
    float ps = ((p0 + p1) + (p2 + p3)) + ((p4 + p5) + (p6 + p7)) +                \
               ((p8 + p9) + (pa + pb)) + ((pc + pd) + (pe + pf));                 \
    PU w0, w1;                                                                    \
    w0.u[0] = cvtpk(p0, p1); w0.u[1] = cvtpk(p2, p3);                             \
    w0.u[2] = cvtpk(p4, p5); w0.u[3] = cvtpk(p6, p7);                             \
    w1.u[0] = cvtpk(p8, p9); w1.u[1] = cvtpk(pa, pb);                             \
    w1.u[2] = cvtpk(pc, pd); w1.u[3] = cvtpk(pe, pf);                             \
    ps += __shfl_xor(ps, 16);                                                     \
    ps += __shfl_xor(ps, 32);                                                     \
    lsum += ps;                                                                   \
    acc0 = __builtin_amdgcn_mfma_f32_16x16x32_bf16(vf00, w0.v, acc0, 0, 0, 0);    \
    acc1 = __builtin_amdgcn_mfma_f32_16x16x32_bf16(vf01, w0.v, acc1, 0, 0, 0);    \
    acc0 = __builtin_amdgcn_mfma_f32_16x16x32_bf16(vf10, w1.v, acc0, 0, 0, 0);    \
    acc1 = __builtin_amdgcn_mfma_f32_16x16x32_bf16(vf11, w1.v, acc1, 0, 0, 0);    \
  }

// fragment reads + compute for one buffer (Kc/Vc static)
#define COMPUTE(Kc, Vc) {                                                         \
    bf16x8 kf0 = *(const bf16x8*)&Kc[(r16) * 40 + g4 * 8];                        \
    bf16x8 kf1 = *(const bf16x8*)&Kc[(16 + r16) * 40 + g4 * 8];                   \
    bf16x8 kf2 = *(const bf16x8*)&Kc[(32 + r16) * 40 + g4 * 8];                   \
    bf16x8 kf3 = *(const bf16x8*)&Kc[(48 + r16) * 40 + g4 * 8];                   \
    bf16x8 vf00 = *(const bf16x8*)&Vc[r16 * 72 + 8 * g4];                         \
    bf16x8 vf01 = *(const bf16x8*)&Vc[(16 + r16) * 72 + 8 * g4];                  \
    bf16x8 vf10 = *(const bf16x8*)&Vc[r16 * 72 + 32 + 8 * g4];                    \
    bf16x8 vf11 = *(const bf16x8*)&Vc[(16 + r16) * 72 + 32 + 8 * g4];             \
    SUBTILE(qfA, lA, accA0, accA1)                                                \
    SUBTILE(qfB, lB, accB0, accB1)                                                \
  }

  // prologue: tile t0p -> buf0, tile t0p+1 -> regs
  LOADT(t0p)
  STORET(kD0, vD0)
  LOADT(t0p + 1)
  __syncthreads();

  // 18 iterations, unrolled x2 with static buffers: pairs t=0..15, then 16, 17
  for (int t = 0; t < 16; t += 2) {
    STORET(kD1, vD1)
    LOADT(t0p + t + 2)
    COMPUTE(Kc0, Vc0)
    __syncthreads();
    STORET(kD0, vD0)
    LOADT(t0p + t + 3)
    COMPUTE(Kc1, Vc1)
    __syncthreads();
  }
  // t=16 (buf0): store t=17 into buf1, no more loads
  STORET(kD1, vD1)
  COMPUTE(Kc0, Vc0)
  __syncthreads();
  // t=17 (buf1)
  COMPUTE(Kc1, Vc1)

  // ---- in-block combine: part1 -> LDS (dead tileset space), part0 adds + writes ----
  __syncthreads();
  float* ex = (float*)&Ks[1][0][0];     // 2 waves x 64 lanes x 16 f32 = 8 KB
  float* lex = ex + 2048;               // 2 waves x 64 lanes x 2 f32
  if (part == 1) {
    f32x4* dst = (f32x4*)&ex[(wsub * 64 + lane) * 16];
    dst[0] = accA0; dst[1] = accA1; dst[2] = accB0; dst[3] = accB1;
    lex[(wsub * 64 + lane) * 2] = lA;
    lex[(wsub * 64 + lane) * 2 + 1] = lB;
  }
  __syncthreads();
  if (part == 0) {
    const f32x4* src = (const f32x4*)&ex[(wsub * 64 + lane) * 16];
    accA0 += src[0]; accA1 += src[1]; accB0 += src[2]; accB1 += src[3];
    lA += lex[(wsub * 64 + lane) * 2];
    lB += lex[(wsub * 64 + lane) * 2 + 1];
    float invA = 1.f / lA;
    float invB = 1.f / lB;
    unsigned short* oA = aT + ((size_t)b * T_ + qbase + r16) * C_ + h * HD + 4 * g4;
    unsigned short* oB = aT + ((size_t)b * T_ + qbase + 16 + r16) * C_ + h * HD + 4 * g4;
    u32x2 wA0 = {cvtpk(accA0[0] * invA, accA0[1] * invA), cvtpk(accA0[2] * invA, accA0[3] * invA)};
    u32x2 wA1 = {cvtpk(accA1[0] * invA, accA1[1] * invA), cvtpk(accA1[2] * invA, accA1[3] * invA)};
    u32x2 wB0 = {cvtpk(accB0[0] * invB, accB0[1] * invB), cvtpk(accB0[2] * invB, accB0[3] * invB)};
    u32x2 wB1 = {cvtpk(accB1[0] * invB, accB1[1] * invB), cvtpk(accB1[2] * invB, accB1[3] * invB)};
    *(u32x2*)oA = wA0;
    *(u32x2*)(oA + 16) = wA1;
    *(u32x2*)oB = wB0;
    *(u32x2*)(oB + 16) = wB1;
  }
#undef LOADT
#undef STORET
#undef SUBTILE
#undef COMPUTE
}

// ---------------- proj GEMM + bias + residual ----------------
__global__ __launch_bounds__(256) void proj_gemm(const unsigned short* W, const unsigned short* aT,
                                                 const float* bias, const float* x, float* out) {
  int b = blockIdx.z;
  int lane = threadIdx.x & 63, w = threadIdx.x >> 6;
  int r16 = lane & 15, g4 = lane >> 4;
  int m0 = blockIdx.y * 64 + (w >> 1) * 32;
  int n0 = blockIdx.x * 64 + (w & 1) * 32;
  const bf16x8* Wv = (const bf16x8*)W;
  const bf16x8* Av = (const bf16x8*)(aT + (size_t)b * T_ * C_);
  f32x4 acc[2][2] = {};
  for (int k0 = 0; k0 < C_; k0 += 32) {
    bf16x8 af[2], bfr[2];
    for (int mi = 0; mi < 2; ++mi)
      af[mi] = Wv[((m0 + mi * 16 + r16) * C_ + k0 + g4 * 8) >> 3];
    for (int ni = 0; ni < 2; ++ni)
      bfr[ni] = Av[((n0 + ni * 16 + r16) * C_ + k0 + g4 * 8) >> 3];
    for (int mi = 0; mi < 2; ++mi)
      for (int ni = 0; ni < 2; ++ni)
        acc[mi][ni] = __builtin_amdgcn_mfma_f32_16x16x32_bf16(af[mi], bfr[ni], acc[mi][ni], 0, 0, 0);
  }
  for (int mi = 0; mi < 2; ++mi)
    for (int ni = 0; ni < 2; ++ni) {
      int t = n0 + ni * 16 + r16;
      for (int r = 0; r < 4; ++r) {
        int o = m0 + mi * 16 + g4 * 4 + r;
        size_t idx = ((size_t)b * C_ + o) * T_ + t;
        out[idx] = x[idx] + acc[mi][ni][r] + bias[o];
      }
    }
}

extern "C" void kernel_launch(void* const* d_in, const int* in_sizes, int n_in,
                              void* d_out, int out_size, void* d_ws, size_t ws_size,
                              hipStream_t stream) {
  const float* x  = (const float*)d_in[0];
  const float* gw = (const float*)d_in[1];
  const float* gb = (const float*)d_in[2];
  const float* wq = (const float*)d_in[3];
  const float* bq = (const float*)d_in[4];
  const float* wp = (const float*)d_in[5];
  const float* bp = (const float*)d_in[6];

  char* ws = (char*)d_ws;
  float* ws1 = (float*)ws;                       // 256*2 f32
  unsigned short* wqb = (unsigned short*)(ws + 4096);
  unsigned short* wpb = wqb + 3 * C_ * C_;
  unsigned short* nT  = wpb + C_ * C_;
  const size_t NE = (size_t)B_ * T_ * C_;        // 2359296
  unsigned short* qT = nT + NE;
  unsigned short* kT = qT + NE;
  unsigned short* vW = kT + NE;
  unsigned short* aT = vW + NE;

  prep<<<1280, 256, 0, stream>>>(wq, wp, x, wqb, wpb, ws1);
  gn_norm<<<dim3(72, 4), 256, 0, stream>>>(x, ws1, gw, gb, nT);
  qkv_gemm<<<dim3(36, 12, 4), 256, 0, stream>>>(wqb, nT, bq, qT, kT, vW);
  attn<<<dim3(36, 8, 4), 256, 0, stream>>>(qT, kT, vW, aT);
  proj_gemm<<<dim3(36, 4, 4), 256, 0, stream>>>(wpb, aT, bp, x, (float*)d_out);
}

// Round 19
// 82.597 us; speedup vs baseline: 1.3208x; 1.2887x over previous
//
#include <hip/hip_runtime.h>

#define B_ 4
#define C_ 256
#define T_ 2304
#define HD 32
#define GSZ (32 * T_)                 // elems per groupnorm group = 73728
#define SCL2E (0.17677669529663687f * 1.44269504088896f)  // (1/sqrt(32)) * log2(e)

typedef short bf16x8 __attribute__((ext_vector_type(8)));
typedef float f32x4 __attribute__((ext_vector_type(4)));
typedef unsigned int u32x2 __attribute__((ext_vector_type(2)));

__device__ inline unsigned short f2bf(float f) {
  unsigned int u = __float_as_uint(f);
  return (unsigned short)((u + 0x7FFFu + ((u >> 16) & 1u)) >> 16);
}

__device__ inline float fexp2(float x) {
  float r;
  asm("v_exp_f32 %0, %1" : "=v"(r) : "v"(x));
  return r;
}

__device__ inline unsigned cvtpk(float lo, float hi) {
  unsigned r;
  asm("v_cvt_pk_bf16_f32 %0, %1, %2" : "=v"(r) : "v"(lo), "v"(hi));
  return r;
}

// ---------------- weights -> bf16  +  groupnorm partial stats (merged) ----------------
__global__ void prep(const float* wq, const float* wp, const float* x,
                     unsigned short* oq, unsigned short* op, float* ws1) {
  if (blockIdx.x < 1024) {
    int i = blockIdx.x * 256 + threadIdx.x;
    const int n1 = 3 * C_ * C_;
    if (i < n1) oq[i] = f2bf(wq[i]);
    else        op[i - n1] = f2bf(wp[i - n1]);
    return;
  }
  int bid = blockIdx.x - 1024;
  int bg = bid >> 3, sl = bid & 7;
  const float4* p = (const float4*)(x + (size_t)bg * GSZ + sl * (GSZ / 8));
  float s = 0.f, q = 0.f;
  for (int it = 0; it < 9; ++it) {
    float4 v = p[it * 256 + threadIdx.x];
    s += v.x + v.y + v.z + v.w;
    q += v.x * v.x + v.y * v.y + v.z * v.z + v.w * v.w;
  }
  for (int off = 32; off; off >>= 1) {
    s += __shfl_down(s, off);
    q += __shfl_down(q, off);
  }
  __shared__ float red[8];
  int w = threadIdx.x >> 6;
  if ((threadIdx.x & 63) == 0) { red[w * 2] = s; red[w * 2 + 1] = q; }
  __syncthreads();
  if (threadIdx.x == 0) {
    float S = red[0] + red[2] + red[4] + red[6];
    float Q = red[1] + red[3] + red[5] + red[7];
    ws1[bid * 2] = S;
    ws1[bid * 2 + 1] = Q;
  }
}

// ---------------- groupnorm: finalize stats (inline) + normalize + transpose to nT[B][T][C] --
__global__ void gn_norm(const float* x, const float* ws1, const float* gamma,
                        const float* beta, unsigned short* nT) {
  int b = blockIdx.y, t0 = blockIdx.x * 32;
  __shared__ unsigned short tile[32 * 264];
  __shared__ float stl[16];
  int tid = threadIdx.x;
  if (tid < 8) {
    float S = 0.f, Q = 0.f;
    for (int sl = 0; sl < 8; ++sl) {
      S += ws1[((b * 8 + tid) * 8 + sl) * 2];
      Q += ws1[((b * 8 + tid) * 8 + sl) * 2 + 1];
    }
    float mean = S / (float)GSZ;
    float var = Q / (float)GSZ - mean * mean;
    stl[tid * 2] = mean;
    stl[tid * 2 + 1] = rsqrtf(var + 1e-5f);
  }
  __syncthreads();
#pragma unroll
  for (int it = 0; it < 8; ++it) {
    int qd = it * 256 + tid;
    int c = qd >> 3, tq = qd & 7;
    float4 v = *(const float4*)&x[((size_t)b * C_ + c) * T_ + t0 + tq * 4];
    int g = c >> 5;
    float mean = stl[g * 2], rstd = stl[g * 2 + 1];
    float sc = rstd * gamma[c];
    float sh = beta[c] - mean * sc;
    tile[(tq * 4 + 0) * 264 + c] = f2bf(v.x * sc + sh);
    tile[(tq * 4 + 1) * 264 + c] = f2bf(v.y * sc + sh);
    tile[(tq * 4 + 2) * 264 + c] = f2bf(v.z * sc + sh);
    tile[(tq * 4 + 3) * 264 + c] = f2bf(v.w * sc + sh);
  }
  __syncthreads();
#pragma unroll
  for (int it = 0; it < 4; ++it) {
    int qd = it * 256 + tid;
    int tt = qd >> 5, c8 = (qd & 31) * 8;
    *(uint4*)&nT[((size_t)b * T_ + t0 + tt) * C_ + c8] = *(const uint4*)&tile[tt * 264 + c8];
  }
}

// ---------------- QKV GEMM: LDS-staged full-K operands + 1 barrier, then pure LDS MFMA -----
// Output path identical to R16: acc -> LDS transpose tile (aliased onto As) -> 16B stores.
__global__ __launch_bounds__(256) void qkv_gemm(const unsigned short* W, const unsigned short* nT,
                                                const float* bias, unsigned short* qT,
                                                unsigned short* kT, unsigned short* vW) {
  __shared__ short As[64 * 264];
  __shared__ short Bs[64 * 264];
  int b = blockIdx.z;
  int tid = threadIdx.x;
  int lane = tid & 63, w = tid >> 6;
  int r16 = lane & 15, g4 = lane >> 4;
  int y = blockIdx.y;
  int type = y >> 2;                    // 0=q 1=k 2=v

  // stage: A = W rows [y*64, +64) x K=256; B = nT rows [bx*64, +64) x K=256
  {
    int r = tid >> 2, c8 = (tid & 3) * 8;
    const unsigned short* Ag = W + (size_t)(y * 64 + r) * C_ + c8;
    const unsigned short* Bg = nT + (size_t)b * T_ * C_ + (size_t)(blockIdx.x * 64 + r) * C_ + c8;
    short* Ad = &As[r * 264 + c8];
    short* Bd = &Bs[r * 264 + c8];
#pragma unroll
    for (int p = 0; p < 8; ++p) {
      *(int4*)(Ad + p * 32) = *(const int4*)(Ag + p * 32);
      *(int4*)(Bd + p * 32) = *(const int4*)(Bg + p * 32);
    }
  }
  __syncthreads();

  int mw = (w >> 1) * 32, nw = (w & 1) * 32;
  f32x4 acc[2][2] = {};
#pragma unroll
  for (int ks = 0; ks < 8; ++ks) {
    bf16x8 a0 = *(const bf16x8*)&As[(mw + r16) * 264 + ks * 32 + g4 * 8];
    bf16x8 a1 = *(const bf16x8*)&As[(mw + 16 + r16) * 264 + ks * 32 + g4 * 8];
    bf16x8 b0 = *(const bf16x8*)&Bs[(nw + r16) * 264 + ks * 32 + g4 * 8];
    bf16x8 b1 = *(const bf16x8*)&Bs[(nw + 16 + r16) * 264 + ks * 32 + g4 * 8];
    acc[0][0] = __builtin_amdgcn_mfma_f32_16x16x32_bf16(a0, b0, acc[0][0], 0, 0, 0);
    acc[0][1] = __builtin_amdgcn_mfma_f32_16x16x32_bf16(a0, b1, acc[0][1], 0, 0, 0);
    acc[1][0] = __builtin_amdgcn_mfma_f32_16x16x32_bf16(a1, b0, acc[1][0], 0, 0, 0);
    acc[1][1] = __builtin_amdgcn_mfma_f32_16x16x32_bf16(a1, b1, acc[1][1], 0, 0, 0);
  }
  __syncthreads();                      // As dead -> reuse as transpose tile

  short* tt = As;                       // [64][72]
#pragma unroll
  for (int mi = 0; mi < 2; ++mi) {
#pragma unroll
    for (int ni = 0; ni < 2; ++ni) {
      int t_loc = (w & 1) * 32 + ni * 16 + r16;
      int o_loc = (w >> 1) * 32 + mi * 16 + g4 * 4;
      int o = y * 64 + o_loc;
      float v0 = acc[mi][ni][0] + bias[o + 0];
      float v1 = acc[mi][ni][1] + bias[o + 1];
      float v2 = acc[mi][ni][2] + bias[o + 2];
      float v3 = acc[mi][ni][3] + bias[o + 3];
      if (type == 0) { v0 *= SCL2E; v1 *= SCL2E; v2 *= SCL2E; v3 *= SCL2E; }
      if (type < 2) {
        u32x2 pw = {cvtpk(v0, v1), cvtpk(v2, v3)};
        *(u32x2*)&tt[t_loc * 72 + o_loc] = pw;    // [t][o]
      } else {
        tt[(o_loc + 0) * 72 + t_loc] = f2bf(v0);  // [o][t]
        tt[(o_loc + 1) * 72 + t_loc] = f2bf(v1);
        tt[(o_loc + 2) * 72 + t_loc] = f2bf(v2);
        tt[(o_loc + 3) * 72 + t_loc] = f2bf(v3);
      }
    }
  }
  __syncthreads();
  if (type < 2) {
    unsigned short* dst = (type == 0) ? qT : kT;
    int obase = y * 64 - type * 256;
    int t_loc = tid >> 2;
    int tg = blockIdx.x * 64 + t_loc;
#pragma unroll
    for (int half = 0; half < 2; ++half) {
      int o_loc = half * 32 + (tid & 3) * 8;
      int o2 = obase + o_loc;
      int hh = o2 >> 5, d = o2 & 31;
      *(uint4*)&dst[(((size_t)b * 8 + hh) * T_ + tg) * HD + d] = *(const uint4*)&tt[t_loc * 72 + o_loc];
    }
  } else {
    int obase = y * 64 - 512;
    int o_loc = tid >> 2;
    int o2 = obase + o_loc;
    int hh = o2 >> 5, d = o2 & 31;
    unsigned short* vdst = vW + ((size_t)(b * 8 + hh) * HD + d) * T_ + blockIdx.x * 64;
#pragma unroll
    for (int half = 0; half < 2; ++half) {
      int t_loc = half * 32 + (tid & 3) * 8;
      *(uint4*)&vdst[t_loc] = *(const uint4*)&tt[o_loc * 72 + t_loc];
    }
  }
}

// ---------------- flash attention: 4 waves = 2 s-parts x 2 q-waves, in-block combine (R16) --
__global__ __launch_bounds__(256) void attn(const unsigned short* qT, const unsigned short* kT,
                                            const unsigned short* vW, unsigned short* aT) {
  int b = blockIdx.z, h = blockIdx.y, qt = blockIdx.x;
  int tid = threadIdx.x, lane = tid & 63, w = tid >> 6;  // w in {0..3}
  int part = w >> 1, wsub = w & 1;
  int r16 = lane & 15, g4 = lane >> 4;
  __shared__ short Ks[2][2][64 * 40];   // [part][buf][s][d] padded to 40
  __shared__ short Vs[2][2][32 * 72];   // [part][buf][d][s] padded to 72
  const unsigned short* qB = qT + ((size_t)b * 8 + h) * T_ * HD;
  const unsigned short* kB = kT + ((size_t)b * 8 + h) * T_ * HD;
  const unsigned short* vB = vW + ((size_t)b * 8 + h) * HD * T_;
  int qbase = qt * 64 + wsub * 32;      // wave owns q-rows [qbase, qbase+32)
  bf16x8 qfA = *(const bf16x8*)(qB + (qbase + r16) * HD + g4 * 8);
  bf16x8 qfB = *(const bf16x8*)(qB + (qbase + 16 + r16) * HD + g4 * 8);
  float lA = 0.f, lB = 0.f;
  f32x4 accA0 = {}, accA1 = {}, accB0 = {}, accB1 = {};
  int t0 = part * 18;

  // staging: each 2-wave part (128 threads) stages its own tileset, 4x b128 per thread
  int tp = tid & 127;
  int krow = tp >> 2, kcol = (tid & 3) * 8;   // K rows krow, krow+32
  int vrow = tp >> 3, vcol = (tid & 7) * 8;   // V rows vrow, vrow+16
  const unsigned short* kSrc = kB + (size_t)krow * HD + kcol;
  const unsigned short* vSrc = vB + (size_t)vrow * T_ + vcol;
  int4 rgK0, rgK1, rgV0, rgV1;

  union PU { unsigned u[4]; bf16x8 v; };
  union VU { int2 d2[2]; bf16x8 v; };

#define LOADT(t_) {                                                               \
    const unsigned short* k_ = kSrc + (t_) * 64 * HD;                             \
    rgK0 = *(const int4*)k_;                                                      \
    rgK1 = *(const int4*)(k_ + 32 * HD);                                          \
    const unsigned short* v_ = vSrc + (t_) * 64;                                  \
    rgV0 = *(const int4*)v_;                                                      \
    rgV1 = *(const int4*)(v_ + (size_t)16 * T_);                                  \
  }

#define STORET(bi) {                                                              \
    short* kD = &Ks[part][bi][krow * 40 + kcol];                                  \
    *(int4*)kD = rgK0;                                                            \
    *(int4*)(kD + 32 * 40) = rgK1;                                                \
    short* vD = &Vs[part][bi][vrow * 72 + vcol];                                  \
    *(int4*)vD = rgV0;                                                            \
    *(int4*)(vD + 16 * 72) = rgV1;                                                \
  }

// QK -> exp -> pack (lane-local) -> PV through registers. kappa(g4,j) = 4g4+(j&3)+16(j>>2).
#define SUBTILE(qf, lsum, acc0, acc1) {                                           \
    f32x4 z = {};                                                                 \
    f32x4 s0 = __builtin_amdgcn_mfma_f32_16x16x32_bf16(kf0, qf, z, 0, 0, 0);      \
    f32x4 s1 = __builtin_amdgcn_mfma_f32_16x16x32_bf16(kf1, qf, z, 0, 0, 0);      \
    f32x4 s2 = __builtin_amdgcn_mfma_f32_16x16x32_bf16(kf2, qf, z, 0, 0, 0);      \
    f32x4 s3 = __builtin_amdgcn_mfma_f32_16x16x32_bf16(kf3, qf, z, 0, 0, 0);      \
    float p0 = fexp2(s0[0]), p1 = fexp2(s0[1]), p2 = fexp2(s0[2]), p3 = fexp2(s0[3]); \
    float p4 = fexp2(s1[0]), p5 = fexp2(s1[1]), p6 = fexp2(s1[2]), p7 = fexp2(s1[3]); \
    float p8 = fexp2(s2[0]), p9 = fexp2(s2[1]), pa = fexp2(s2[2]), pb = fexp2(s2[3]); \
    float pc = fexp2(s3[0]), pd = fexp2(s3[1]), pe = fexp2(s3[2]), pf = fexp2(s3[3]); \
    float ps = ((p0 + p1) + (p2 + p3)) + ((p4 + p5) + (p6 + p7)) +                \
               ((p8 + p9) + (pa + pb)) + ((pc + pd) + (pe + pf));                 \
    PU w0, w1;                                                                    \
    w0.u[0] = cvtpk(p0, p1); w0.u[1] = cvtpk(p2, p3);                             \
    w0.u[2] = cvtpk(p4, p5); w0.u[3] = cvtpk(p6, p7);                             \
    w1.u[0] = cvtpk(p8, p9); w1.u[1] = cvtpk(pa, pb);                             \
    w1.u[2] = cvtpk(pc, pd); w1.u[3] = cvtpk(pe, pf);                             \
    ps += __shfl_xor(ps, 16);                                                     \
    ps += __shfl_xor(ps, 32);                                                     \
    lsum += ps;                                                                   \
    acc0 = __builtin_amdgcn_mfma_f32_16x16x32_bf16(vf00.v, w0.v, acc0, 0, 0, 0);  \
    acc1 = __builtin_amdgcn_mfma_f32_16x16x32_bf16(vf01.v, w0.v, acc1, 0, 0, 0);  \
    acc0 = __builtin_amdgcn_mfma_f32_16x16x32_bf16(vf10.v, w1.v, acc0, 0, 0, 0);  \
    acc1 = __builtin_amdgcn_mfma_f32_16x16x32_bf16(vf11.v, w1.v, acc1, 0, 0, 0);  \
  }

  // prologue: tile t0 -> buf0, tile t0+1 -> regs
  LOADT(t0)
  STORET(0)
  LOADT(t0 + 1)
  __syncthreads();

  for (int t = 0; t < 18; ++t) {
    int bi = t & 1;
    if (t < 17) STORET(bi ^ 1)          // tile t+1: regs -> other buffer
    if (t < 16) LOADT(t0 + t + 2)       // tile t+2: global -> regs

    const short* Kc = &Ks[part][bi][0];
    const short* Vc = &Vs[part][bi][0];
    bf16x8 kf0 = *(const bf16x8*)&Kc[(r16) * 40 + g4 * 8];
    bf16x8 kf1 = *(const bf16x8*)&Kc[(16 + r16) * 40 + g4 * 8];
    bf16x8 kf2 = *(const bf16x8*)&Kc[(32 + r16) * 40 + g4 * 8];
    bf16x8 kf3 = *(const bf16x8*)&Kc[(48 + r16) * 40 + g4 * 8];
    VU vf00, vf01, vf10, vf11;
    {
      const short* vr0 = Vc + r16 * 72;
      const short* vr1 = Vc + (16 + r16) * 72;
      vf00.d2[0] = *(const int2*)(vr0 + 4 * g4);
      vf00.d2[1] = *(const int2*)(vr0 + 16 + 4 * g4);
      vf01.d2[0] = *(const int2*)(vr1 + 4 * g4);
      vf01.d2[1] = *(const int2*)(vr1 + 16 + 4 * g4);
      vf10.d2[0] = *(const int2*)(vr0 + 32 + 4 * g4);
      vf10.d2[1] = *(const int2*)(vr0 + 48 + 4 * g4);
      vf11.d2[0] = *(const int2*)(vr1 + 32 + 4 * g4);
      vf11.d2[1] = *(const int2*)(vr1 + 48 + 4 * g4);
    }

    SUBTILE(qfA, lA, accA0, accA1)
    SUBTILE(qfB, lB, accB0, accB1)

    __syncthreads();                    // tile t consumed; tile t+1 stores visible
  }

  // ---- in-block combine: part1 -> LDS (dead tileset-1 space), part0 adds + writes ----
  float* ex = (float*)&Ks[1][0][0];     // 2 waves x 64 lanes x 16 f32 = 8 KB
  float* lex = ex + 2048;               // 2 waves x 64 lanes x 2 f32
  if (part == 1) {
    f32x4* dst = (f32x4*)&ex[(wsub * 64 + lane) * 16];
    dst[0] = accA0; dst[1] = accA1; dst[2] = accB0; dst[3] = accB1;
    lex[(wsub * 64 + lane) * 2] = lA;
    lex[(wsub * 64 + lane) * 2 + 1] = lB;
  }
  __syncthreads();
  if (part == 0) {
    const f32x4* src = (const f32x4*)&ex[(wsub * 64 + lane) * 16];
    accA0 += src[0]; accA1 += src[1]; accB0 += src[2]; accB1 += src[3];
    lA += lex[(wsub * 64 + lane) * 2];
    lB += lex[(wsub * 64 + lane) * 2 + 1];
    float invA = 1.f / lA;
    float invB = 1.f / lB;
    unsigned short* oA = aT + ((size_t)b * T_ + qbase + r16) * C_ + h * HD + 4 * g4;
    unsigned short* oB = aT + ((size_t)b * T_ + qbase + 16 + r16) * C_ + h * HD + 4 * g4;
    u32x2 wA0 = {cvtpk(accA0[0] * invA, accA0[1] * invA), cvtpk(accA0[2] * invA, accA0[3] * invA)};
    u32x2 wA1 = {cvtpk(accA1[0] * invA, accA1[1] * invA), cvtpk(accA1[2] * invA, accA1[3] * invA)};
    u32x2 wB0 = {cvtpk(accB0[0] * invB, accB0[1] * invB), cvtpk(accB0[2] * invB, accB0[3] * invB)};
    u32x2 wB1 = {cvtpk(accB1[0] * invB, accB1[1] * invB), cvtpk(accB1[2] * invB, accB1[3] * invB)};
    *(u32x2*)oA = wA0;
    *(u32x2*)(oA + 16) = wA1;
    *(u32x2*)oB = wB0;
    *(u32x2*)(oB + 16) = wB1;
  }
#undef LOADT
#undef STORET
#undef SUBTILE
}

// ---------------- proj GEMM: LDS-staged operands + bias + residual ----------------
__global__ __launch_bounds__(256) void proj_gemm(const unsigned short* W, const unsigned short* aT,
                                                 const float* bias, const float* x, float* out) {
  __shared__ short As[64 * 264];
  __shared__ short Bs[64 * 264];
  int b = blockIdx.z;
  int tid = threadIdx.x;
  int lane = tid & 63, w = tid >> 6;
  int r16 = lane & 15, g4 = lane >> 4;

  {
    int r = tid >> 2, c8 = (tid & 3) * 8;
    const unsigned short* Ag = W + (size_t)(blockIdx.y * 64 + r) * C_ + c8;
    const unsigned short* Bg = aT + (size_t)b * T_ * C_ + (size_t)(blockIdx.x * 64 + r) * C_ + c8;
    short* Ad = &As[r * 264 + c8];
    short* Bd = &Bs[r * 264 + c8];
#pragma unroll
    for (int p = 0; p < 8; ++p) {
      *(int4*)(Ad + p * 32) = *(const int4*)(Ag + p * 32);
      *(int4*)(Bd + p * 32) = *(const int4*)(Bg + p * 32);
    }
  }
  __syncthreads();

  int mw = (w >> 1) * 32, nw = (w & 1) * 32;
  f32x4 acc[2][2] = {};
#pragma unroll
  for (int ks = 0; ks < 8; ++ks) {
    bf16x8 a0 = *(const bf16x8*)&As[(mw + r16) * 264 + ks * 32 + g4 * 8];
    bf16x8 a1 = *(const bf16x8*)&As[(mw + 16 + r16) * 264 + ks * 32 + g4 * 8];
    bf16x8 b0 = *(const bf16x8*)&Bs[(nw + r16) * 264 + ks * 32 + g4 * 8];
    bf16x8 b1 = *(const bf16x8*)&Bs[(nw + 16 + r16) * 264 + ks * 32 + g4 * 8];
    acc[0][0] = __builtin_amdgcn_mfma_f32_16x16x32_bf16(a0, b0, acc[0][0], 0, 0, 0);
    acc[0][1] = __builtin_amdgcn_mfma_f32_16x16x32_bf16(a0, b1, acc[0][1], 0, 0, 0);
    acc[1][0] = __builtin_amdgcn_mfma_f32_16x16x32_bf16(a1, b0, acc[1][0], 0, 0, 0);
    acc[1][1] = __builtin_amdgcn_mfma_f32_16x16x32_bf16(a1, b1, acc[1][1], 0, 0, 0);
  }
  int m0 = blockIdx.y * 64 + mw;
  int n0 = blockIdx.x * 64 + nw;
  for (int mi = 0; mi < 2; ++mi)
    for (int ni = 0; ni < 2; ++ni) {
      int t = n0 + ni * 16 + r16;
      for (int r = 0; r < 4; ++r) {
        int o = m0 + mi * 16 + g4 * 4 + r;
        size_t idx = ((size_t)b * C_ + o) * T_ + t;
        out[idx] = x[idx] + acc[mi][ni][r] + bias[o];
      }
    }
}

extern "C" void kernel_launch(void* const* d_in, const int* in_sizes, int n_in,
                              void* d_out, int out_size, void* d_ws, size_t ws_size,
                              hipStream_t stream) {
  const float* x  = (const float*)d_in[0];
  const float* gw = (const float*)d_in[1];
  const float* gb = (const float*)d_in[2];
  const float* wq = (const float*)d_in[3];
  const float* bq = (const float*)d_in[4];
  const float* wp = (const float*)d_in[5];
  const float* bp = (const float*)d_in[6];

  char* ws = (char*)d_ws;
  float* ws1 = (float*)ws;                       // 256*2 f32
  unsigned short* wqb = (unsigned short*)(ws + 4096);
  unsigned short* wpb = wqb + 3 * C_ * C_;
  unsigned short* nT  = wpb + C_ * C_;
  const size_t NE = (size_t)B_ * T_ * C_;        // 2359296
  unsigned short* qT = nT + NE;
  unsigned short* kT = qT + NE;
  unsigned short* vW = kT + NE;
  unsigned short* aT = vW + NE;

  prep<<<1280, 256, 0, stream>>>(wq, wp, x, wqb, wpb, ws1);
  gn_norm<<<dim3(72, 4), 256, 0, stream>>>(x, ws1, gw, gb, nT);
  qkv_gemm<<<dim3(36, 12, 4), 256, 0, stream>>>(wqb, nT, bq, qT, kT, vW);
  attn<<<dim3(36, 8, 4), 256, 0, stream>>>(qT, kT, vW, aT);
  proj_gemm<<<dim3(36, 4, 4), 256, 0, stream>>>(wpb, aT, bp, x, (float*)d_out);
}

// Round 20
// 79.587 us; speedup vs baseline: 1.3707x; 1.0378x over previous
//
#include <hip/hip_runtime.h>

#define B_ 4
#define C_ 256
#define T_ 2304
#define HD 32
#define GSZ (32 * T_)                 // elems per groupnorm group = 73728
#define SCL2E (0.17677669529663687f * 1.44269504088896f)  // (1/sqrt(32)) * log2(e)

typedef short bf16x8 __attribute__((ext_vector_type(8)));
typedef float f32x4 __attribute__((ext_vector_type(4)));
typedef unsigned int u32x2 __attribute__((ext_vector_type(2)));

__device__ inline unsigned short f2bf(float f) {
  unsigned int u = __float_as_uint(f);
  return (unsigned short)((u + 0x7FFFu + ((u >> 16) & 1u)) >> 16);
}

__device__ inline float fexp2(float x) {
  float r;
  asm("v_exp_f32 %0, %1" : "=v"(r) : "v"(x));
  return r;
}

__device__ inline unsigned cvtpk(float lo, float hi) {
  unsigned r;
  asm("v_cvt_pk_bf16_f32 %0, %1, %2" : "=v"(r) : "v"(lo), "v"(hi));
  return r;
}

// ---------------- weights -> bf16  +  groupnorm partial stats (merged) ----------------
__global__ void prep(const float* wq, const float* wp, const float* x,
                     unsigned short* oq, unsigned short* op, float* ws1) {
  if (blockIdx.x < 1024) {
    int i = blockIdx.x * 256 + threadIdx.x;
    const int n1 = 3 * C_ * C_;
    if (i < n1) oq[i] = f2bf(wq[i]);
    else        op[i - n1] = f2bf(wp[i - n1]);
    return;
  }
  int bid = blockIdx.x - 1024;
  int bg = bid >> 3, sl = bid & 7;
  const float4* p = (const float4*)(x + (size_t)bg * GSZ + sl * (GSZ / 8));
  float s = 0.f, q = 0.f;
  for (int it = 0; it < 9; ++it) {
    float4 v = p[it * 256 + threadIdx.x];
    s += v.x + v.y + v.z + v.w;
    q += v.x * v.x + v.y * v.y + v.z * v.z + v.w * v.w;
  }
  for (int off = 32; off; off >>= 1) {
    s += __shfl_down(s, off);
    q += __shfl_down(q, off);
  }
  __shared__ float red[8];
  int w = threadIdx.x >> 6;
  if ((threadIdx.x & 63) == 0) { red[w * 2] = s; red[w * 2 + 1] = q; }
  __syncthreads();
  if (threadIdx.x == 0) {
    float S = red[0] + red[2] + red[4] + red[6];
    float Q = red[1] + red[3] + red[5] + red[7];
    ws1[bid * 2] = S;
    ws1[bid * 2 + 1] = Q;
  }
}

// ---------------- groupnorm: finalize stats (inline) + normalize + transpose to nT[B][T][C] --
__global__ void gn_norm(const float* x, const float* ws1, const float* gamma,
                        const float* beta, unsigned short* nT) {
  int b = blockIdx.y, t0 = blockIdx.x * 32;
  __shared__ unsigned short tile[32 * 264];
  __shared__ float stl[16];
  int tid = threadIdx.x;
  if (tid < 8) {
    float S = 0.f, Q = 0.f;
    for (int sl = 0; sl < 8; ++sl) {
      S += ws1[((b * 8 + tid) * 8 + sl) * 2];
      Q += ws1[((b * 8 + tid) * 8 + sl) * 2 + 1];
    }
    float mean = S / (float)GSZ;
    float var = Q / (float)GSZ - mean * mean;
    stl[tid * 2] = mean;
    stl[tid * 2 + 1] = rsqrtf(var + 1e-5f);
  }
  __syncthreads();
#pragma unroll
  for (int it = 0; it < 8; ++it) {
    int qd = it * 256 + tid;
    int c = qd >> 3, tq = qd & 7;
    float4 v = *(const float4*)&x[((size_t)b * C_ + c) * T_ + t0 + tq * 4];
    int g = c >> 5;
    float mean = stl[g * 2], rstd = stl[g * 2 + 1];
    float sc = rstd * gamma[c];
    float sh = beta[c] - mean * sc;
    tile[(tq * 4 + 0) * 264 + c] = f2bf(v.x * sc + sh);
    tile[(tq * 4 + 1) * 264 + c] = f2bf(v.y * sc + sh);
    tile[(tq * 4 + 2) * 264 + c] = f2bf(v.z * sc + sh);
    tile[(tq * 4 + 3) * 264 + c] = f2bf(v.w * sc + sh);
  }
  __syncthreads();
#pragma unroll
  for (int it = 0; it < 4; ++it) {
    int qd = it * 256 + tid;
    int tt = qd >> 5, c8 = (qd & 31) * 8;
    *(uint4*)&nT[((size_t)b * T_ + t0 + tt) * C_ + c8] = *(const uint4*)&tile[tt * 264 + c8];
  }
}

// ---------------- QKV GEMM: LDS-staged full-K operands + 1 barrier, then pure LDS MFMA -----
__global__ __launch_bounds__(256) void qkv_gemm(const unsigned short* W, const unsigned short* nT,
                                                const float* bias, unsigned short* qT,
                                                unsigned short* kT, unsigned short* vW) {
  __shared__ short As[64 * 264];
  __shared__ short Bs[64 * 264];
  int b = blockIdx.z;
  int tid = threadIdx.x;
  int lane = tid & 63, w = tid >> 6;
  int r16 = lane & 15, g4 = lane >> 4;
  int y = blockIdx.y;
  int type = y >> 2;                    // 0=q 1=k 2=v

  {
    int r = tid >> 2, c8 = (tid & 3) * 8;
    const unsigned short* Ag = W + (size_t)(y * 64 + r) * C_ + c8;
    const unsigned short* Bg = nT + (size_t)b * T_ * C_ + (size_t)(blockIdx.x * 64 + r) * C_ + c8;
    short* Ad = &As[r * 264 + c8];
    short* Bd = &Bs[r * 264 + c8];
#pragma unroll
    for (int p = 0; p < 8; ++p) {
      *(int4*)(Ad + p * 32) = *(const int4*)(Ag + p * 32);
      *(int4*)(Bd + p * 32) = *(const int4*)(Bg + p * 32);
    }
  }
  __syncthreads();

  int mw = (w >> 1) * 32, nw = (w & 1) * 32;
  f32x4 acc[2][2] = {};
#pragma unroll
  for (int ks = 0; ks < 8; ++ks) {
    bf16x8 a0 = *(const bf16x8*)&As[(mw + r16) * 264 + ks * 32 + g4 * 8];
    bf16x8 a1 = *(const bf16x8*)&As[(mw + 16 + r16) * 264 + ks * 32 + g4 * 8];
    bf16x8 b0 = *(const bf16x8*)&Bs[(nw + r16) * 264 + ks * 32 + g4 * 8];
    bf16x8 b1 = *(const bf16x8*)&Bs[(nw + 16 + r16) * 264 + ks * 32 + g4 * 8];
    acc[0][0] = __builtin_amdgcn_mfma_f32_16x16x32_bf16(a0, b0, acc[0][0], 0, 0, 0);
    acc[0][1] = __builtin_amdgcn_mfma_f32_16x16x32_bf16(a0, b1, acc[0][1], 0, 0, 0);
    acc[1][0] = __builtin_amdgcn_mfma_f32_16x16x32_bf16(a1, b0, acc[1][0], 0, 0, 0);
    acc[1][1] = __builtin_amdgcn_mfma_f32_16x16x32_bf16(a1, b1, acc[1][1], 0, 0, 0);
  }
  __syncthreads();                      // As dead -> reuse as transpose tile

  short* tt = As;                       // [64][72]
#pragma unroll
  for (int mi = 0; mi < 2; ++mi) {
#pragma unroll
    for (int ni = 0; ni < 2; ++ni) {
      int t_loc = (w & 1) * 32 + ni * 16 + r16;
      int o_loc = (w >> 1) * 32 + mi * 16 + g4 * 4;
      int o = y * 64 + o_loc;
      float v0 = acc[mi][ni][0] + bias[o + 0];
      float v1 = acc[mi][ni][1] + bias[o + 1];
      float v2 = acc[mi][ni][2] + bias[o + 2];
      float v3 = acc[mi][ni][3] + bias[o + 3];
      if (type == 0) { v0 *= SCL2E; v1 *= SCL2E; v2 *= SCL2E; v3 *= SCL2E; }
      if (type < 2) {
        u32x2 pw = {cvtpk(v0, v1), cvtpk(v2, v3)};
        *(u32x2*)&tt[t_loc * 72 + o_loc] = pw;    // [t][o]
      } else {
        tt[(o_loc + 0) * 72 + t_loc] = f2bf(v0);  // [o][t]
        tt[(o_loc + 1) * 72 + t_loc] = f2bf(v1);
        tt[(o_loc + 2) * 72 + t_loc] = f2bf(v2);
        tt[(o_loc + 3) * 72 + t_loc] = f2bf(v3);
      }
    }
  }
  __syncthreads();
  if (type < 2) {
    unsigned short* dst = (type == 0) ? qT : kT;
    int obase = y * 64 - type * 256;
    int t_loc = tid >> 2;
    int tg = blockIdx.x * 64 + t_loc;
#pragma unroll
    for (int half = 0; half < 2; ++half) {
      int o_loc = half * 32 + (tid & 3) * 8;
      int o2 = obase + o_loc;
      int hh = o2 >> 5, d = o2 & 31;
      *(uint4*)&dst[(((size_t)b * 8 + hh) * T_ + tg) * HD + d] = *(const uint4*)&tt[t_loc * 72 + o_loc];
    }
  } else {
    int obase = y * 64 - 512;
    int o_loc = tid >> 2;
    int o2 = obase + o_loc;
    int hh = o2 >> 5, d = o2 & 31;
    unsigned short* vdst = vW + ((size_t)(b * 8 + hh) * HD + d) * T_ + blockIdx.x * 64;
#pragma unroll
    for (int half = 0; half < 2; ++half) {
      int t_loc = half * 32 + (tid & 3) * 8;
      *(uint4*)&vdst[t_loc] = *(const uint4*)&tt[o_loc * 72 + t_loc];
    }
  }
}

// ---------------- flash attention: l-sum via ones-MFMA (no ps adds, no shfl) ----------------
// 4 waves = 2 s-parts x 2 q-waves; 64-s tiles double-buffered; in-block combine.
__global__ __launch_bounds__(256) void attn(const unsigned short* qT, const unsigned short* kT,
                                            const unsigned short* vW, unsigned short* aT) {
  int b = blockIdx.z, h = blockIdx.y, qt = blockIdx.x;
  int tid = threadIdx.x, lane = tid & 63, w = tid >> 6;  // w in {0..3}
  int part = w >> 1, wsub = w & 1;
  int r16 = lane & 15, g4 = lane >> 4;
  __shared__ short Ks[2][2][64 * 40];   // [part][buf][s][d] padded to 40
  __shared__ short Vs[2][2][32 * 72];   // [part][buf][d][s] padded to 72
  const unsigned short* qB = qT + ((size_t)b * 8 + h) * T_ * HD;
  const unsigned short* kB = kT + ((size_t)b * 8 + h) * T_ * HD;
  const unsigned short* vB = vW + ((size_t)b * 8 + h) * HD * T_;
  int qbase = qt * 64 + wsub * 32;      // wave owns q-rows [qbase, qbase+32)
  bf16x8 qfA = *(const bf16x8*)(qB + (qbase + r16) * HD + g4 * 8);
  bf16x8 qfB = *(const bf16x8*)(qB + (qbase + 16 + r16) * HD + g4 * 8);
  const short OB = (short)0x3F80;       // bf16 1.0
  const bf16x8 ones = {OB, OB, OB, OB, OB, OB, OB, OB};
  f32x4 accA0 = {}, accA1 = {}, accB0 = {}, accB1 = {};
  f32x4 accLA = {}, accLB = {};
  int t0 = part * 18;

  // staging: each 2-wave part (128 threads) stages its own tileset, 4x b128 per thread
  int tp = tid & 127;
  int krow = tp >> 2, kcol = (tid & 3) * 8;   // K rows krow, krow+32
  int vrow = tp >> 3, vcol = (tid & 7) * 8;   // V rows vrow, vrow+16
  const unsigned short* kSrc = kB + (size_t)krow * HD + kcol;
  const unsigned short* vSrc = vB + (size_t)vrow * T_ + vcol;
  int4 rgK0, rgK1, rgV0, rgV1;

  union PU { unsigned u[4]; bf16x8 v; };
  union VU { int2 d2[2]; bf16x8 v; };

#define LOADT(t_) {                                                               \
    const unsigned short* k_ = kSrc + (t_) * 64 * HD;                             \
    rgK0 = *(const int4*)k_;                                                      \
    rgK1 = *(const int4*)(k_ + 32 * HD);                                          \
    const unsigned short* v_ = vSrc + (t_) * 64;                                  \
    rgV0 = *(const int4*)v_;                                                      \
    rgV1 = *(const int4*)(v_ + (size_t)16 * T_);                                  \
  }

#define STORET(bi) {                                                              \
    short* kD = &Ks[part][bi][krow * 40 + kcol];                                  \
    *(int4*)kD = rgK0;                                                            \
    *(int4*)(kD + 32 * 40) = rgK1;                                                \
    short* vD = &Vs[part][bi][vrow * 72 + vcol];                                  \
    *(int4*)vD = rgV0;                                                            \
    *(int4*)(vD + 16 * 72) = rgV1;                                                \
  }

// QK -> exp -> pack (lane-local) -> PV + l-sum entirely through the matrix pipe.
#define SUBTILE(qf, accL, acc0, acc1) {                                           \
    f32x4 z = {};                                                                 \
    f32x4 s0 = __builtin_amdgcn_mfma_f32_16x16x32_bf16(kf0, qf, z, 0, 0, 0);      \
    f32x4 s1 = __builtin_amdgcn_mfma_f32_16x16x32_bf16(kf1, qf, z, 0, 0, 0);      \
    f32x4 s2 = __builtin_amdgcn_mfma_f32_16x16x32_bf16(kf2, qf, z, 0, 0, 0);      \
    f32x4 s3 = __builtin_amdgcn_mfma_f32_16x16x32_bf16(kf3, qf, z, 0, 0, 0);      \
    float p0 = fexp2(s0[0]), p1 = fexp2(s0[1]), p2 = fexp2(s0[2]), p3 = fexp2(s0[3]); \
    float p4 = fexp2(s1[0]), p5 = fexp2(s1[1]), p6 = fexp2(s1[2]), p7 = fexp2(s1[3]); \
    float p8 = fexp2(s2[0]), p9 = fexp2(s2[1]), pa = fexp2(s2[2]), pb = fexp2(s2[3]); \
    float pc = fexp2(s3[0]), pd = fexp2(s3[1]), pe = fexp2(s3[2]), pf = fexp2(s3[3]); \
    PU w0, w1;                                                                    \
    w0.u[0] = cvtpk(p0, p1); w0.u[1] = cvtpk(p2, p3);                             \
    w0.u[2] = cvtpk(p4, p5); w0.u[3] = cvtpk(p6, p7);                             \
    w1.u[0] = cvtpk(p8, p9); w1.u[1] = cvtpk(pa, pb);                             \
    w1.u[2] = cvtpk(pc, pd); w1.u[3] = cvtpk(pe, pf);                             \
    accL = __builtin_amdgcn_mfma_f32_16x16x32_bf16(ones, w0.v, accL, 0, 0, 0);    \
    accL = __builtin_amdgcn_mfma_f32_16x16x32_bf16(ones, w1.v, accL, 0, 0, 0);    \
    acc0 = __builtin_amdgcn_mfma_f32_16x16x32_bf16(vf00.v, w0.v, acc0, 0, 0, 0);  \
    acc1 = __builtin_amdgcn_mfma_f32_16x16x32_bf16(vf01.v, w0.v, acc1, 0, 0, 0);  \
    acc0 = __builtin_amdgcn_mfma_f32_16x16x32_bf16(vf10.v, w1.v, acc0, 0, 0, 0);  \
    acc1 = __builtin_amdgcn_mfma_f32_16x16x32_bf16(vf11.v, w1.v, acc1, 0, 0, 0);  \
  }

  // prologue: tile t0 -> buf0, tile t0+1 -> regs
  LOADT(t0)
  STORET(0)
  LOADT(t0 + 1)
  __syncthreads();

  for (int t = 0; t < 18; ++t) {
    int bi = t & 1;
    if (t < 17) STORET(bi ^ 1)          // tile t+1: regs -> other buffer
    if (t < 16) LOADT(t0 + t + 2)       // tile t+2: global -> regs

    const short* Kc = &Ks[part][bi][0];
    const short* Vc = &Vs[part][bi][0];
    bf16x8 kf0 = *(const bf16x8*)&Kc[(r16) * 40 + g4 * 8];
    bf16x8 kf1 = *(const bf16x8*)&Kc[(16 + r16) * 40 + g4 * 8];
    bf16x8 kf2 = *(const bf16x8*)&Kc[(32 + r16) * 40 + g4 * 8];
    bf16x8 kf3 = *(const bf16x8*)&Kc[(48 + r16) * 40 + g4 * 8];
    VU vf00, vf01, vf10, vf11;
    {
      const short* vr0 = Vc + r16 * 72;
      const short* vr1 = Vc + (16 + r16) * 72;
      vf00.d2[0] = *(const int2*)(vr0 + 4 * g4);
      vf00.d2[1] = *(const int2*)(vr0 + 16 + 4 * g4);
      vf01.d2[0] = *(const int2*)(vr1 + 4 * g4);
      vf01.d2[1] = *(const int2*)(vr1 + 16 + 4 * g4);
      vf10.d2[0] = *(const int2*)(vr0 + 32 + 4 * g4);
      vf10.d2[1] = *(const int2*)(vr0 + 48 + 4 * g4);
      vf11.d2[0] = *(const int2*)(vr1 + 32 + 4 * g4);
      vf11.d2[1] = *(const int2*)(vr1 + 48 + 4 * g4);
    }

    SUBTILE(qfA, accLA, accA0, accA1)
    SUBTILE(qfB, accLB, accB0, accB1)

    __syncthreads();                    // tile t consumed; tile t+1 stores visible
  }

  float lA = accLA[0];
  float lB = accLB[0];

  // ---- in-block combine: part1 -> LDS (dead tileset-1 space), part0 adds + writes ----
  float* ex = (float*)&Ks[1][0][0];     // 2 waves x 64 lanes x 16 f32 = 8 KB
  float* lex = ex + 2048;               // 2 waves x 64 lanes x 2 f32
  if (part == 1) {
    f32x4* dst = (f32x4*)&ex[(wsub * 64 + lane) * 16];
    dst[0] = accA0; dst[1] = accA1; dst[2] = accB0; dst[3] = accB1;
    lex[(wsub * 64 + lane) * 2] = lA;
    lex[(wsub * 64 + lane) * 2 + 1] = lB;
  }
  __syncthreads();
  if (part == 0) {
    const f32x4* src = (const f32x4*)&ex[(wsub * 64 + lane) * 16];
    accA0 += src[0]; accA1 += src[1]; accB0 += src[2]; accB1 += src[3];
    lA += lex[(wsub * 64 + lane) * 2];
    lB += lex[(wsub * 64 + lane) * 2 + 1];
    float invA = 1.f / lA;
    float invB = 1.f / lB;
    unsigned short* oA = aT + ((size_t)b * T_ + qbase + r16) * C_ + h * HD + 4 * g4;
    unsigned short* oB = aT + ((size_t)b * T_ + qbase + 16 + r16) * C_ + h * HD + 4 * g4;
    u32x2 wA0 = {cvtpk(accA0[0] * invA, accA0[1] * invA), cvtpk(accA0[2] * invA, accA0[3] * invA)};
    u32x2 wA1 = {cvtpk(accA1[0] * invA, accA1[1] * invA), cvtpk(accA1[2] * invA, accA1[3] * invA)};
    u32x2 wB0 = {cvtpk(accB0[0] * invB, accB0[1] * invB), cvtpk(accB0[2] * invB, accB0[3] * invB)};
    u32x2 wB1 = {cvtpk(accB1[0] * invB, accB1[1] * invB), cvtpk(accB1[2] * invB, accB1[3] * invB)};
    *(u32x2*)oA = wA0;
    *(u32x2*)(oA + 16) = wA1;
    *(u32x2*)oB = wB0;
    *(u32x2*)(oB + 16) = wB1;
  }
#undef LOADT
#undef STORET
#undef SUBTILE
}

// ---------------- proj GEMM: LDS-staged operands + bias + residual ----------------
__global__ __launch_bounds__(256) void proj_gemm(const unsigned short* W, const unsigned short* aT,
                                                 const float* bias, const float* x, float* out) {
  __shared__ short As[64 * 264];
  __shared__ short Bs[64 * 264];
  int b = blockIdx.z;
  int tid = threadIdx.x;
  int lane = tid & 63, w = tid >> 6;
  int r16 = lane & 15, g4 = lane >> 4;

  {
    int r = tid >> 2, c8 = (tid & 3) * 8;
    const unsigned short* Ag = W + (size_t)(blockIdx.y * 64 + r) * C_ + c8;
    const unsigned short* Bg = aT + (size_t)b * T_ * C_ + (size_t)(blockIdx.x * 64 + r) * C_ + c8;
    short* Ad = &As[r * 264 + c8];
    short* Bd = &Bs[r * 264 + c8];
#pragma unroll
    for (int p = 0; p < 8; ++p) {
      *(int4*)(Ad + p * 32) = *(const int4*)(Ag + p * 32);
      *(int4*)(Bd + p * 32) = *(const int4*)(Bg + p * 32);
    }
  }
  __syncthreads();

  int mw = (w >> 1) * 32, nw = (w & 1) * 32;
  f32x4 acc[2][2] = {};
#pragma unroll
  for (int ks = 0; ks < 8; ++ks) {
    bf16x8 a0 = *(const bf16x8*)&As[(mw + r16) * 264 + ks * 32 + g4 * 8];
    bf16x8 a1 = *(const bf16x8*)&As[(mw + 16 + r16) * 264 + ks * 32 + g4 * 8];
    bf16x8 b0 = *(const bf16x8*)&Bs[(nw + r16) * 264 + ks * 32 + g4 * 8];
    bf16x8 b1 = *(const bf16x8*)&Bs[(nw + 16 + r16) * 264 + ks * 32 + g4 * 8];
    acc[0][0] = __builtin_amdgcn_mfma_f32_16x16x32_bf16(a0, b0, acc[0][0], 0, 0, 0);
    acc[0][1] = __builtin_amdgcn_mfma_f32_16x16x32_bf16(a0, b1, acc[0][1], 0, 0, 0);
    acc[1][0] = __builtin_amdgcn_mfma_f32_16x16x32_bf16(a1, b0, acc[1][0], 0, 0, 0);
    acc[1][1] = __builtin_amdgcn_mfma_f32_16x16x32_bf16(a1, b1, acc[1][1], 0, 0, 0);
  }
  int m0 = blockIdx.y * 64 + mw;
  int n0 = blockIdx.x * 64 + nw;
  for (int mi = 0; mi < 2; ++mi)
    for (int ni = 0; ni < 2; ++ni) {
      int t = n0 + ni * 16 + r16;
      for (int r = 0; r < 4; ++r) {
        int o = m0 + mi * 16 + g4 * 4 + r;
        size_t idx = ((size_t)b * C_ + o) * T_ + t;
        out[idx] = x[idx] + acc[mi][ni][r] + bias[o];
      }
    }
}

extern "C" void kernel_launch(void* const* d_in, const int* in_sizes, int n_in,
                              void* d_out, int out_size, void* d_ws, size_t ws_size,
                              hipStream_t stream) {
  const float* x  = (const float*)d_in[0];
  const float* gw = (const float*)d_in[1];
  const float* gb = (const float*)d_in[2];
  const float* wq = (const float*)d_in[3];
  const float* bq = (const float*)d_in[4];
  const float* wp = (const float*)d_in[5];
  const float* bp = (const float*)d_in[6];

  char* ws = (char*)d_ws;
  float* ws1 = (float*)ws;                       // 256*2 f32
  unsigned short* wqb = (unsigned short*)(ws + 4096);
  unsigned short* wpb = wqb + 3 * C_ * C_;
  unsigned short* nT  = wpb + C_ * C_;
  const size_t NE = (size_t)B_ * T_ * C_;        // 2359296
  unsigned short* qT = nT + NE;
  unsigned short* kT = qT + NE;
  unsigned short* vW = kT + NE;
  unsigned short* aT = vW + NE;

  prep<<<1280, 256, 0, stream>>>(wq, wp, x, wqb, wpb, ws1);
  gn_norm<<<dim3(72, 4), 256, 0, stream>>>(x, ws1, gw, gb, nT);
  qkv_gemm<<<dim3(36, 12, 4), 256, 0, stream>>>(wqb, nT, bq, qT, kT, vW);
  attn<<<dim3(36, 8, 4), 256, 0, stream>>>(qT, kT, vW, aT);
  proj_gemm<<<dim3(36, 4, 4), 256, 0, stream>>>(wpb, aT, bp, x, (float*)d_out);
}